// Round 2
// 3304.589 us; speedup vs baseline: 1.5123x; 1.5123x over previous
//
#include <hip/hip_runtime.h>
#include <hip/hip_bf16.h>

#define V_    32000
#define H_    512
#define DEPTH_ 6
#define B_    8
#define L_    256
#define TA_   200
#define TT_   100
#define AD_   1024
#define DI_   1024
#define DS_   16
#define DTR_  32
#define M_    (B_*L_)   // 2048 tokens

typedef __hip_bfloat16 bf16;
static __device__ __forceinline__ float b2f(bf16 x){ return __bfloat162float(x); }
static __device__ __forceinline__ float siluf(float x){ return x / (1.f + __expf(-x)); }

// dtype-adaptive input load: F32=true -> buffer holds float32, else bf16
template<bool F32>
static __device__ __forceinline__ float ld(const void* p, size_t i){
    if (F32) return ((const float*)p)[i];
    else     return __bfloat162float(((const bf16*)p)[i]);
}

// ---------- MFMA helpers ----------
typedef __attribute__((ext_vector_type(8))) short s16x8;   // 8 bf16 = 4 VGPR
typedef __attribute__((ext_vector_type(4))) float f32x4;   // 4 f32 acc

static __device__ __forceinline__ short f2bf_s(float f){
    union { bf16 b; short s; } u; u.b = __float2bfloat16(f); return u.s;
}
static __device__ __forceinline__ float bf_s2f(short s){
    union { bf16 b; short s2; } u; u.s2 = s; return __bfloat162float(u.b);
}
// split f32 into hi+lo bf16 so hi+lo ~= f with ~2^-17 rel error
static __device__ __forceinline__ void split2(float f, short &h, short &l){
    h = f2bf_s(f);
    l = f2bf_s(f - bf_s2f(h));
}

// ---------- dtype detection ----------
__global__ void detect_kernel(const bf16* __restrict__ tok, int* __restrict__ flag){
    __shared__ int s;
    if (threadIdx.x==0) s = 0;
    __syncthreads();
    for (int i=threadIdx.x; i<4096; i+=256){
        float v = b2f(tok[i]);
        if (!(fabsf(v) < 1e3f)) atomicOr(&s, 1);   // catches NaN/inf/huge
    }
    __syncthreads();
    if (threadIdx.x==0) *flag = s;
}

// ---------- stage 1: pooled conditioning ----------
template<bool F32>
__global__ void feat_sum_kernel(const void* __restrict__ feats, const unsigned char* __restrict__ mask,
                                int T, float* __restrict__ out, const int* __restrict__ fl)
{
    if ((*fl!=0)!=F32) return;
    int d = blockIdx.x*256 + threadIdx.x;
    int b = blockIdx.y;
    const unsigned char* mb = mask + b*T;
    float s = 0.f;
    for (int t=0;t<T;t++) if (!mb[t]) s += ld<F32>(feats, (size_t)b*T*AD_ + (size_t)t*AD_ + d);
    out[b*AD_+d] = s;
}

__global__ void count_kernel(const unsigned char* __restrict__ am, const unsigned char* __restrict__ tm,
                             float* __restrict__ cnt /* 2*B */)
{
    int i = threadIdx.x;
    if (i < B_)        { int c=0; for (int t=0;t<TA_;t++) c += am[i*TA_+t]?0:1; cnt[i] = (float)c; }
    else if (i < 2*B_) { int b=i-B_; int c=0; for (int t=0;t<TT_;t++) c += tm[b*TT_+t]?0:1; cnt[B_+b]=(float)c; }
}

template<bool F32>
__global__ __launch_bounds__(256) void pooled_kernel(const float* __restrict__ sa, const float* __restrict__ st,
    const float* __restrict__ cnt, const void* __restrict__ Wa, const void* __restrict__ ab,
    const void* __restrict__ Wt, const void* __restrict__ tb, const void* __restrict__ me,
    float* __restrict__ pooled, const int* __restrict__ fl)
{
    if ((*fl!=0)!=F32) return;
    int b = blockIdx.x;
    __shared__ float s_a[AD_], s_t[AD_];
    for (int i=threadIdx.x;i<AD_;i+=256){ s_a[i]=sa[b*AD_+i]; s_t[i]=st[b*AD_+i]; }
    __syncthreads();
    float ca = cnt[b], ct = cnt[B_+b];
    float denom = fmaxf(ca+ct, 1.0f);
    for (int h=threadIdx.x; h<H_; h+=256){
        float acc = 0.f;
        for (int k=0;k<AD_;k++) acc = fmaf(s_a[k], ld<F32>(Wa,(size_t)h*AD_+k), acc);
        for (int k=0;k<AD_;k++) acc = fmaf(s_t[k], ld<F32>(Wt,(size_t)h*AD_+k), acc);
        acc += ca*(ld<F32>(ab,h) + ld<F32>(me,h));
        acc += ct*(ld<F32>(tb,h) + ld<F32>(me,H_+h));
        pooled[b*H_+h] = acc/denom;
    }
}

template<bool F32>
__global__ __launch_bounds__(256) void cond_kernel(const float* __restrict__ pooled,
    const void* __restrict__ cw, const void* __restrict__ cb, float* __restrict__ cond,
    const int* __restrict__ fl)
{
    if ((*fl!=0)!=F32) return;
    int b = blockIdx.x;
    __shared__ float ps[H_];
    for (int i=threadIdx.x;i<H_;i+=256) ps[i]=pooled[b*H_+i];
    __syncthreads();
    for (int h=threadIdx.x; h<H_; h+=256){
        float acc = ld<F32>(cb,h);
        for (int k=0;k<H_;k++) acc = fmaf(ps[k], ld<F32>(cw,(size_t)h*H_+k), acc);
        cond[b*H_+h] = acc;
    }
}

template<bool F32>
__global__ void embed_kernel(const int* __restrict__ ids, const void* __restrict__ tok,
    const void* __restrict__ pos, const float* __restrict__ cond, float* __restrict__ x,
    const int* __restrict__ fl)
{
    if ((*fl!=0)!=F32) return;
    int tid = blockIdx.x*256 + threadIdx.x;
    if (tid >= M_*H_) return;
    int m = tid >> 9, h = tid & (H_-1);
    int b = m >> 8, l = m & (L_-1);
    x[tid] = ld<F32>(tok,(size_t)ids[m]*H_ + h) + ld<F32>(pos,(size_t)l*H_+h) + cond[b*H_+h];
}

// ---------- MFMA split-bf16 GEMM: C(M,N) = A(M,K)f32 @ B(N,K)^T ----------
// A is split into hi/lo bf16 (2 passes); if B is f32 it is split too and an
// extra hi*lo pass runs (3 passes total). Dropped al*bl term is ~2^-18 rel.
// Tile 128x128, BK=32, 4 waves each computing a 64x64 sub-tile (4x4 frags of
// 16x16x32 MFMA). LDS row stride 40 shorts (80B = 5*16B): rows 16B-aligned for
// ds_read_b128 and each 8-lane fragment-read group covers all 32 banks once.
// MLOOP: block iterates m-tiles keeping its B column panel L2-resident.
template<bool F32>
__global__ __launch_bounds__(256) void gemm_kernel(const float* __restrict__ A, const void* __restrict__ Bw,
    float* __restrict__ Cf, void* __restrict__ Cb, const void* __restrict__ bias,
    int M, int N, int K, int MLOOP, const int* __restrict__ fl)
{
    if ((*fl!=0)!=F32) return;
    __shared__ short Ah[128][40];
    __shared__ short Al[128][40];
    __shared__ short Bh[128][40];
    __shared__ short Bl[128][40];

    const int tid = threadIdx.x;
    const int l    = tid & 63;
    const int wid  = tid >> 6;
    const int wr   = wid >> 1, wc = wid & 1;   // wave -> 64x64 quadrant
    const int lrow = l & 15;
    const int lk   = (l >> 4) << 3;            // k-offset 0,8,16,24
    const int n0   = blockIdx.x * 128;

    for (int mt = 0; mt < MLOOP; ++mt){
        const int m0 = (blockIdx.y * MLOOP + mt) * 128;
        f32x4 acc[4][4] = {};

        for (int k0 = 0; k0 < K; k0 += 32){
            // ---- stage A tile: 128x32 f32 -> hi/lo bf16 ----
            #pragma unroll
            for (int p=0;p<4;p++){
                int fidx = (p<<8) + tid;          // 0..1023 float4 slots
                int row  = fidx >> 3;             // 0..127
                int kq   = (fidx & 7) << 2;       // 0,4,...,28
                float4 v = *(const float4*)(A + (size_t)(m0+row)*K + k0 + kq);
                short4 h, lo;
                split2(v.x, h.x, lo.x);
                split2(v.y, h.y, lo.y);
                split2(v.z, h.z, lo.z);
                split2(v.w, h.w, lo.w);
                *(short4*)&Ah[row][kq] = h;
                *(short4*)&Al[row][kq] = lo;
            }
            // ---- stage B tile ----
            if (F32){
                #pragma unroll
                for (int p=0;p<4;p++){
                    int fidx = (p<<8) + tid;
                    int row  = fidx >> 3;
                    int kq   = (fidx & 7) << 2;
                    float4 v = *(const float4*)((const float*)Bw + (size_t)(n0+row)*K + k0 + kq);
                    short4 h, lo;
                    split2(v.x, h.x, lo.x);
                    split2(v.y, h.y, lo.y);
                    split2(v.z, h.z, lo.z);
                    split2(v.w, h.w, lo.w);
                    *(short4*)&Bh[row][kq] = h;
                    *(short4*)&Bl[row][kq] = lo;
                }
            } else {
                #pragma unroll
                for (int p=0;p<2;p++){
                    int fidx = (p<<8) + tid;      // 0..511 short8 slots
                    int row  = fidx >> 2;         // 0..127
                    int kq   = (fidx & 3) << 3;   // 0,8,16,24
                    s16x8 v = *(const s16x8*)((const short*)Bw + (size_t)(n0+row)*K + k0 + kq);
                    *(s16x8*)&Bh[row][kq] = v;
                }
            }
            __syncthreads();

            // ---- fragments + MFMA ----
            s16x8 fah[4], fal[4], fbh[4], fbl[4];
            #pragma unroll
            for (int i=0;i<4;i++){
                int ar = wr*64 + i*16 + lrow;
                fah[i] = *(const s16x8*)&Ah[ar][lk];
                fal[i] = *(const s16x8*)&Al[ar][lk];
                int br = wc*64 + i*16 + lrow;
                fbh[i] = *(const s16x8*)&Bh[br][lk];
                if (F32) fbl[i] = *(const s16x8*)&Bl[br][lk];
            }
            #pragma unroll
            for (int i=0;i<4;i++){
                #pragma unroll
                for (int j=0;j<4;j++){
                    acc[i][j] = __builtin_amdgcn_mfma_f32_16x16x32_bf16(fah[i], fbh[j], acc[i][j], 0,0,0);
                    acc[i][j] = __builtin_amdgcn_mfma_f32_16x16x32_bf16(fal[i], fbh[j], acc[i][j], 0,0,0);
                    if (F32)
                        acc[i][j] = __builtin_amdgcn_mfma_f32_16x16x32_bf16(fah[i], fbl[j], acc[i][j], 0,0,0);
                }
            }
            __syncthreads();
        }

        // ---- epilogue: D row=(l>>4)*4+r, col=l&15 (m89-verified) ----
        const int rbase = (l >> 4) << 2;
        #pragma unroll
        for (int i=0;i<4;i++){
            int mrow = m0 + wr*64 + i*16 + rbase;
            #pragma unroll
            for (int j=0;j<4;j++){
                int ncol = n0 + wc*64 + j*16 + lrow;
                float bv = bias ? ld<F32>(bias,(size_t)ncol) : 0.f;
                #pragma unroll
                for (int r=0;r<4;r++){
                    float outv = acc[i][j][r] + bv;
                    if (Cb){
                        if (F32) ((float*)Cb)[(size_t)(mrow+r)*N+ncol] = outv;
                        else     ((bf16*)Cb)[(size_t)(mrow+r)*N+ncol] = __float2bfloat16(outv);
                    } else {
                        Cf[(size_t)(mrow+r)*N+ncol] = outv;
                    }
                }
            }
        }
    }
}

// ---------- per-layer small kernels ----------
template<bool F32>
__global__ void conv_silu_kernel(const float* __restrict__ xz, const void* __restrict__ cw,
                                 const void* __restrict__ cb, float* __restrict__ xc,
                                 const int* __restrict__ fl)
{
    if ((*fl!=0)!=F32) return;
    int tid = blockIdx.x*256 + threadIdx.x;
    if (tid >= M_*DI_) return;
    int m = tid >> 10, d = tid & (DI_-1);
    int l = m & (L_-1);
    float acc = ld<F32>(cb,d);
    #pragma unroll
    for (int k=0;k<4;k++){
        int l2 = l - 3 + k;
        if (l2 >= 0) acc = fmaf(xz[(size_t)(m-3+k)*(2*DI_) + d], ld<F32>(cw,(size_t)d*4+k), acc);
    }
    xc[tid] = siluf(acc);
}

template<bool F32>
__global__ __launch_bounds__(256) void xproj_kernel(const float* __restrict__ xc,
    const void* __restrict__ xpw, float* __restrict__ dbl, const int* __restrict__ fl)
{
    if ((*fl!=0)!=F32) return;
    int m = blockIdx.x;
    __shared__ float xs[DI_];
    __shared__ float part[64][5];
    for (int i=threadIdx.x;i<DI_;i+=256) xs[i] = xc[(size_t)m*DI_ + i];
    __syncthreads();
    int n = threadIdx.x & 63, c = threadIdx.x >> 6;
    const float* xv = xs + c*256;
    size_t wo = (size_t)n*DI_ + c*256;
    float acc = 0.f;
    for (int k=0;k<256;k++) acc = fmaf(xv[k], ld<F32>(xpw, wo+k), acc);
    part[n][c] = acc;
    __syncthreads();
    if (threadIdx.x < 64){
        dbl[(size_t)m*64 + threadIdx.x] = part[threadIdx.x][0]+part[threadIdx.x][1]
                                        + part[threadIdx.x][2]+part[threadIdx.x][3];
    }
}

template<bool F32>
__global__ __launch_bounds__(256) void dt_kernel(const float* __restrict__ dbl, const void* __restrict__ dtw,
    const void* __restrict__ dtb, float* __restrict__ dt, const int* __restrict__ fl)
{
    if ((*fl!=0)!=F32) return;
    int tid = blockIdx.x*256 + threadIdx.x;   // block = 256 consecutive d of one m
    int m = tid >> 10;
    int d = tid & (DI_-1);
    __shared__ float ds_[DTR_];
    if (threadIdx.x < DTR_) ds_[threadIdx.x] = dbl[(size_t)m*64 + threadIdx.x];
    __syncthreads();
    float acc = ld<F32>(dtb,d);
    #pragma unroll
    for (int j=0;j<DTR_;j++) acc = fmaf(ds_[j], ld<F32>(dtw,(size_t)d*DTR_+j), acc);
    float sp = acc > 0.f ? acc + log1pf(__expf(-acc)) : log1pf(__expf(acc));
    dt[tid] = sp;
}

// ---------- fused selective scan ----------
template<bool F32>
__global__ __launch_bounds__(256) void scan_kernel(const float* __restrict__ dt, const float* __restrict__ xc,
    const float* __restrict__ dbl, const float* __restrict__ xz,
    const void* __restrict__ Alog, const void* __restrict__ Dsk,
    float* __restrict__ ys, const int* __restrict__ fl)
{
    if ((*fl!=0)!=F32) return;
    int tid = threadIdx.x;
    int s = tid & 15, dloc = tid >> 4;
    int d = blockIdx.x*16 + dloc;
    int b = blockIdx.y;
    float aA = -__expf(ld<F32>(Alog,(size_t)d*DS_+s));
    float dp = ld<F32>(Dsk,d);
    float h = 0.f;
    int m0 = b*L_;
    float dtc = dt[(size_t)m0*DI_ + d];
    float xcc = xc[(size_t)m0*DI_ + d];
    float Bc  = dbl[(size_t)m0*64 + 32 + s];
    float Cc  = dbl[(size_t)m0*64 + 48 + s];
    for (int t=0;t<L_;t++){
        int m  = m0 + t;
        int mn = m + (t < L_-1 ? 1 : 0);
        float dtn = dt[(size_t)mn*DI_ + d];
        float xcn = xc[(size_t)mn*DI_ + d];
        float Bn  = dbl[(size_t)mn*64 + 32 + s];
        float Cn  = dbl[(size_t)mn*64 + 48 + s];
        float dA = __expf(dtc * aA);
        h = fmaf(h, dA, dtc*Bc*xcc);
        float p = h*Cc;
        p += __shfl_xor(p, 1, 16);
        p += __shfl_xor(p, 2, 16);
        p += __shfl_xor(p, 4, 16);
        p += __shfl_xor(p, 8, 16);
        if (s == 0){
            float zv = xz[(size_t)m*(2*DI_) + DI_ + d];
            ys[(size_t)m*DI_ + d] = (p + dp*xcc) * siluf(zv);
        }
        dtc=dtn; xcc=xcn; Bc=Bn; Cc=Cn;
    }
}

// ---------- residual add + layernorm (block per token) ----------
template<bool F32>
__global__ __launch_bounds__(256) void add_ln_kernel(float* __restrict__ x, const float* __restrict__ yp,
    const void* __restrict__ g, const void* __restrict__ bt, const int* __restrict__ fl)
{
    if ((*fl!=0)!=F32) return;
    int m = blockIdx.x;
    int tid = threadIdx.x;
    float r0 = x[(size_t)m*H_ + tid]       + yp[(size_t)m*H_ + tid];
    float r1 = x[(size_t)m*H_ + tid + 256] + yp[(size_t)m*H_ + tid + 256];
    float s = r0 + r1, q = r0*r0 + r1*r1;
    #pragma unroll
    for (int off=32; off>=1; off>>=1){ s += __shfl_xor(s, off, 64); q += __shfl_xor(q, off, 64); }
    __shared__ float ss[4], qq[4];
    int w = tid >> 6;
    if ((tid & 63)==0){ ss[w]=s; qq[w]=q; }
    __syncthreads();
    float S = ss[0]+ss[1]+ss[2]+ss[3];
    float Q = qq[0]+qq[1]+qq[2]+qq[3];
    float mean = S / (float)H_;
    float var  = Q / (float)H_ - mean*mean;
    float inv  = rsqrtf(var + 1e-5f);
    x[(size_t)m*H_+tid]       = (r0-mean)*inv*ld<F32>(g,tid)     + ld<F32>(bt,tid);
    x[(size_t)m*H_+tid+256]   = (r1-mean)*inv*ld<F32>(g,tid+256) + ld<F32>(bt,tid+256);
}

#define DUAL(kern, grid, block, ...) do { \
    kern<false><<<grid, block, 0, stream>>>(__VA_ARGS__); \
    kern<true><<<grid, block, 0, stream>>>(__VA_ARGS__); } while(0)

extern "C" void kernel_launch(void* const* d_in, const int* in_sizes, int n_in,
                              void* d_out, int out_size, void* d_ws, size_t ws_size,
                              hipStream_t stream)
{
    const int*  ids = (const int*)d_in[0];
    const void* af  = d_in[1];
    const void* tf  = d_in[2];
    const unsigned char* am = (const unsigned char*)d_in[3];
    const unsigned char* tm = (const unsigned char*)d_in[4];
    const void* tok = d_in[5];
    const void* pos = d_in[6];
    const void* aw  = d_in[7];
    const void* ab  = d_in[8];
    const void* tw  = d_in[9];
    const void* tbb = d_in[10];
    const void* me  = d_in[11];
    const void* cw  = d_in[12];
    const void* cb  = d_in[13];
    const void* ipw = d_in[14];
    const void* cvw = d_in[15];
    const void* cvb = d_in[16];
    const void* xpw = d_in[17];
    const void* dtw = d_in[18];
    const void* dtb = d_in[19];
    const void* Alg = d_in[20];
    const void* Dsk = d_in[21];
    const void* ow  = d_in[22];
    const void* lng = d_in[23];
    const void* lnb = d_in[24];
    const void* hw  = d_in[25];
    const void* hb  = d_in[26];

    float* ws   = (float*)d_ws;
    float* x    = ws;                        // M*H
    float* xz   = x    + (size_t)M_*H_;      // M*2DI
    float* xc   = xz   + (size_t)M_*2*DI_;   // M*DI
    float* dbl  = xc   + (size_t)M_*DI_;     // M*64
    float* dtv  = dbl  + (size_t)M_*64;      // M*DI
    float* ysb  = dtv  + (size_t)M_*DI_;     // M*DI
    float* ypj  = ysb  + (size_t)M_*DI_;     // M*H
    float* sa   = ypj  + (size_t)M_*H_;      // B*AD
    float* st   = sa   + B_*AD_;
    float* cnt  = st   + B_*AD_;             // 2*B
    float* pooled = cnt + 2*B_;              // B*H
    float* cond = pooled + B_*H_;            // B*H
    int*   dflag = (int*)(cond + B_*H_);

    detect_kernel<<<1, 256, 0, stream>>>((const bf16*)tok, dflag);

    DUAL(feat_sum_kernel, dim3(AD_/256, B_), 256, af, am, TA_, sa, dflag);
    DUAL(feat_sum_kernel, dim3(AD_/256, B_), 256, tf, tm, TT_, st, dflag);
    count_kernel<<<1, 64, 0, stream>>>(am, tm, cnt);
    DUAL(pooled_kernel, B_, 256, sa, st, cnt, aw, ab, tw, tbb, me, pooled, dflag);
    DUAL(cond_kernel, B_, 256, pooled, cw, cb, cond, dflag);
    DUAL(embed_kernel, (M_*H_+255)/256, 256, ids, tok, pos, cond, x, dflag);

    for (int layer=0; layer<DEPTH_; ++layer){
        size_t o_ipw = (size_t)layer*2*DI_*H_;
        size_t o_cvw = (size_t)layer*DI_*4;
        size_t o_cvb = (size_t)layer*DI_;
        size_t o_xpw = (size_t)layer*64*DI_;
        size_t o_dtw = (size_t)layer*DI_*DTR_;
        size_t o_dtb = (size_t)layer*DI_;
        size_t o_alg = (size_t)layer*DI_*DS_;
        size_t o_dsk = (size_t)layer*DI_;
        size_t o_ow  = (size_t)layer*H_*DI_;
        size_t o_ln  = (size_t)layer*H_;
        const void* ipw_h = (const void*)((const bf16*)ipw + o_ipw);
        const void* ipw_f = (const void*)((const float*)ipw + o_ipw);
        const void* cvw_h = (const void*)((const bf16*)cvw + o_cvw);
        const void* cvw_f = (const void*)((const float*)cvw + o_cvw);
        const void* cvb_h = (const void*)((const bf16*)cvb + o_cvb);
        const void* cvb_f = (const void*)((const float*)cvb + o_cvb);
        const void* xpw_h = (const void*)((const bf16*)xpw + o_xpw);
        const void* xpw_f = (const void*)((const float*)xpw + o_xpw);
        const void* dtw_h = (const void*)((const bf16*)dtw + o_dtw);
        const void* dtw_f = (const void*)((const float*)dtw + o_dtw);
        const void* dtb_h = (const void*)((const bf16*)dtb + o_dtb);
        const void* dtb_f = (const void*)((const float*)dtb + o_dtb);
        const void* alg_h = (const void*)((const bf16*)Alg + o_alg);
        const void* alg_f = (const void*)((const float*)Alg + o_alg);
        const void* dsk_h = (const void*)((const bf16*)Dsk + o_dsk);
        const void* dsk_f = (const void*)((const float*)Dsk + o_dsk);
        const void* ow_h  = (const void*)((const bf16*)ow + o_ow);
        const void* ow_f  = (const void*)((const float*)ow + o_ow);
        const void* lng_h = (const void*)((const bf16*)lng + o_ln);
        const void* lng_f = (const void*)((const float*)lng + o_ln);
        const void* lnb_h = (const void*)((const bf16*)lnb + o_ln);
        const void* lnb_f = (const void*)((const float*)lnb + o_ln);

        gemm_kernel<false><<<dim3(2*DI_/128, M_/128), 256, 0, stream>>>(x, ipw_h, xz, nullptr, nullptr, M_, 2*DI_, H_, 1, dflag);
        gemm_kernel<true ><<<dim3(2*DI_/128, M_/128), 256, 0, stream>>>(x, ipw_f, xz, nullptr, nullptr, M_, 2*DI_, H_, 1, dflag);
        conv_silu_kernel<false><<<(M_*DI_+255)/256, 256, 0, stream>>>(xz, cvw_h, cvb_h, xc, dflag);
        conv_silu_kernel<true ><<<(M_*DI_+255)/256, 256, 0, stream>>>(xz, cvw_f, cvb_f, xc, dflag);
        xproj_kernel<false><<<M_, 256, 0, stream>>>(xc, xpw_h, dbl, dflag);
        xproj_kernel<true ><<<M_, 256, 0, stream>>>(xc, xpw_f, dbl, dflag);
        dt_kernel<false><<<M_*DI_/256, 256, 0, stream>>>(dbl, dtw_h, dtb_h, dtv, dflag);
        dt_kernel<true ><<<M_*DI_/256, 256, 0, stream>>>(dbl, dtw_f, dtb_f, dtv, dflag);
        scan_kernel<false><<<dim3(DI_/16, B_), 256, 0, stream>>>(dtv, xc, dbl, xz, alg_h, dsk_h, ysb, dflag);
        scan_kernel<true ><<<dim3(DI_/16, B_), 256, 0, stream>>>(dtv, xc, dbl, xz, alg_f, dsk_f, ysb, dflag);
        gemm_kernel<false><<<dim3(H_/128, M_/128), 256, 0, stream>>>(ysb, ow_h, ypj, nullptr, nullptr, M_, H_, DI_, 1, dflag);
        gemm_kernel<true ><<<dim3(H_/128, M_/128), 256, 0, stream>>>(ysb, ow_f, ypj, nullptr, nullptr, M_, H_, DI_, 1, dflag);
        add_ln_kernel<false><<<M_, 256, 0, stream>>>(x, ypj, lng_h, lnb_h, dflag);
        add_ln_kernel<true ><<<M_, 256, 0, stream>>>(x, ypj, lng_f, lnb_f, dflag);
    }

    // head: MLOOP=8 -> grid (250,2); each block keeps its 128-col B panel
    // L2-resident across 8 m-tiles (B HBM traffic 1.05GB -> ~131MB)
    DUAL(gemm_kernel, dim3(V_/128, M_/(128*8)), 256, x, hw, nullptr, d_out, hb, M_, V_, H_, 8, dflag);
}